// Round 13
// baseline (4049.384 us; speedup 1.0000x reference)
//
#include <hip/hip_runtime.h>

// Problem constants
#define Bn 4
#define Nn 8192
#define Dn 64
#define Sn 2048
#define Kn 32
#define R2c 0.04f          // f32(0.2*0.2) — same bits as np/jax weak-scalar cast
#define OUT_XYZ (Bn*Sn*3)  // 24576 floats of new_xyz, then feats

// Workspace layout (units = 4-byte elements)
#define WS_P4  0            // [B*N] float4 {x,y,z,0}
#define WS_W1T 131072       // W1^T [67][64]
#define WS_W2T 135360       // W2^T [64][128]
#define WS_W3T 143552       // W3^T [128][256]
#define WS_GRP 176320       // int grp_idx [B*S][K]

#define KPAD 36             // padded LDS row stride (floats) for h tiles

// FPS geometry: 1024 threads x 8 points/thread (4 float2 pairs)
#define FTH 1024
#define FWV (FTH / 64)      // 16 waves

// ---------------------------------------------------------------------------
// Prep: xyz -> float4 array and weights -> [C][O] layout
// ---------------------------------------------------------------------------
__global__ __launch_bounds__(256) void prep_kernel(const float* __restrict__ xyz,
                                                   const float* __restrict__ W1,
                                                   const float* __restrict__ W2,
                                                   const float* __restrict__ W3,
                                                   float* __restrict__ ws) {
    int id = blockIdx.x * 256 + threadIdx.x;
    if (id < Bn * Nn) {
        float4* p4 = (float4*)(ws + WS_P4);
        p4[id] = make_float4(xyz[id * 3 + 0], xyz[id * 3 + 1], xyz[id * 3 + 2], 0.f);
    }
    int i1 = id - Bn * Nn;
    if (i1 >= 0 && i1 < 64 * 67)  { int o = i1 / 67,  c = i1 % 67;  ws[WS_W1T + c * 64  + o] = W1[i1]; }
    int i2 = i1 - 64 * 67;
    if (i2 >= 0 && i2 < 128 * 64) { int o = i2 / 64,  c = i2 % 64;  ws[WS_W2T + c * 128 + o] = W2[i2]; }
    int i3 = i2 - 128 * 64;
    if (i3 >= 0 && i3 < 256 * 128){ int o = i3 / 128, c = i3 % 128; ws[WS_W3T + c * 256 + o] = W3[i3]; }
}

// Packed f32 ops (VOP3P): two independent IEEE f32 lanes per instruction —
// per-element results bit-identical to scalar v_add_f32 / v_mul_f32.
__device__ __forceinline__ float2 pk_add(float2 a, float2 b) {
    float2 d;
    asm("v_pk_add_f32 %0, %1, %2" : "=v"(d) : "v"(a), "v"(b));
    return d;
}
__device__ __forceinline__ float2 pk_mul(float2 a, float2 b) {
    float2 d;
    asm("v_pk_mul_f32 %0, %1, %2" : "=v"(d) : "v"(a), "v"(b));
    return d;
}

// DPP wave-64 max: row_shr 1/2/4/8 within 16-lane rows, then row_bcast 15/31;
// lane 63 holds the full-wave max. bound_ctrl=true injects 0 (harmless: d>=0).
__device__ __forceinline__ float wave_fmax_dpp(float x) {
    float t;
    t = __int_as_float(__builtin_amdgcn_update_dpp(0, __float_as_int(x), 0x111, 0xf, 0xf, true)); x = fmaxf(x, t);
    t = __int_as_float(__builtin_amdgcn_update_dpp(0, __float_as_int(x), 0x112, 0xf, 0xf, true)); x = fmaxf(x, t);
    t = __int_as_float(__builtin_amdgcn_update_dpp(0, __float_as_int(x), 0x114, 0xf, 0xf, true)); x = fmaxf(x, t);
    t = __int_as_float(__builtin_amdgcn_update_dpp(0, __float_as_int(x), 0x118, 0xf, 0xf, true)); x = fmaxf(x, t);
    t = __int_as_float(__builtin_amdgcn_update_dpp(0, __float_as_int(x), 0x142, 0xf, 0xf, true)); x = fmaxf(x, t);
    t = __int_as_float(__builtin_amdgcn_update_dpp(0, __float_as_int(x), 0x143, 0xf, 0xf, true)); x = fmaxf(x, t);
    return __int_as_float(__builtin_amdgcn_readlane(__float_as_int(x), 63));
}

// ---------------------------------------------------------------------------
// Farthest point sampling — R13: 1024 threads x 8 pts (4 float2 pairs),
// amdgpu_waves_per_eu(1,4) (R12 proved this attribute moves the allocator;
// cap 128 VGPRs for 4 waves/SIMD — the ~60-reg working set fits, unlike
// R11's 32-VGPR allocation), packed v_pk_* distance math (bit-exact per
// element; px + (-cx) == px - cx exactly in IEEE754).
// 4 waves/SIMD doubles latency hiding over all prior rounds (R4-R12 ran
// 2 waves/SIMD and were stall-bound, not issue-bound).
// Reduce = R8 structure: value-only DPP wave max -> rare-path
// first-occurrence index recovery -> one barrier -> 16-key lexicographic
// scan ((val<<32)|~p: max val, min p on tie == np.argmax) -> uniform L2
// winner fetch. Centroid history in LDS, coalesced dump at end.
// ---------------------------------------------------------------------------
__global__ __launch_bounds__(FTH)
__attribute__((amdgpu_waves_per_eu(1, 4)))
void fps_kernel(const float* __restrict__ ws, float* __restrict__ out_xyz) {
    #pragma clang fp contract(off)
    const int b = blockIdx.x;
    const int tid = threadIdx.x;
    const float4* p4 = (const float4*)(ws + WS_P4) + b * Nn;

    // pair i holds points j=2i (.x) and j=2i+1 (.y); p = j*FTH + tid
    float2 px2[4], py2[4], pz2[4], ds2[4];
    #pragma unroll
    for (int i = 0; i < 4; i++) {
        float4 v0 = p4[(2 * i)     * FTH + tid];
        float4 v1 = p4[(2 * i + 1) * FTH + tid];
        px2[i] = make_float2(v0.x, v1.x);
        py2[i] = make_float2(v0.y, v1.y);
        pz2[i] = make_float2(v0.z, v1.z);
        ds2[i] = make_float2(1e10f, 1e10f);   // matches np.float32(1e10)
    }
    // Forbid remat re-loads of the point set inside the loop.
    #pragma unroll
    for (int i = 0; i < 4; i++) {
        asm volatile("" : "+v"(px2[i]), "+v"(py2[i]), "+v"(pz2[i]), "+v"(ds2[i]));
    }

    __shared__ unsigned long long sKey[2][FWV];
    __shared__ float sHist[Sn * 3];

    float4 c0 = p4[0];
    float cx = c0.x, cy = c0.y, cz = c0.z;

    for (int s = 0; s < Sn; s++) {
        const int par = s & 1;
        if (tid == 0) {                 // record carry centroid (LDS, cheap)
            sHist[s * 3 + 0] = cx;
            sHist[s * 3 + 1] = cy;
            sHist[s * 3 + 2] = cz;
        }
        // packed dist update: per pair 8 pk + 2 min + 2 max.
        // a + (-c) is bit-identical to a - c; pk halves are independent IEEE
        // f32 ops, so per-element rounding == reference scalar order.
        float2 ncx = make_float2(-cx, -cx);
        float2 ncy = make_float2(-cy, -cy);
        float2 ncz = make_float2(-cz, -cz);
        float lv = -1.0f;
        #pragma unroll
        for (int i = 0; i < 4; i++) {
            float2 dx = pk_add(px2[i], ncx);
            float2 dy = pk_add(py2[i], ncy);
            float2 dz = pk_add(pz2[i], ncz);
            float2 xx = pk_mul(dx, dx);
            float2 yy = pk_mul(dy, dy);
            float2 zz = pk_mul(dz, dz);
            float2 ss = pk_add(xx, yy);       // (dx*dx + dy*dy)
            float2 dd = pk_add(ss, zz);       // ... + dz*dz
            ds2[i].x = fminf(ds2[i].x, dd.x);
            ds2[i].y = fminf(ds2[i].y, dd.y);
            lv = fmaxf(lv, ds2[i].x);         // value-only: order-invariant
            lv = fmaxf(lv, ds2[i].y);
        }
        float wmax = wave_fmax_dpp(lv);
        // rare-path index recovery: descending j keeps min p (first occur.)
        int pb = 0x7fffffff;
        bool match = (lv == wmax);
        if (match) {
            #pragma unroll
            for (int i = 3; i >= 0; i--) {
                if (ds2[i].y == wmax) pb = (2 * i + 1) * FTH + tid;
                if (ds2[i].x == wmax) pb = (2 * i)     * FTH + tid;
            }
        }
        unsigned long long mask = __ballot(match);  // >=1 lane set
        int cand;
        if (__popcll(mask) == 1) {                  // common case
            cand = __builtin_amdgcn_readlane(pb, (int)(__ffsll(mask) - 1));
        } else {                                    // exact value tie (~rare)
            int v = pb;
            #pragma unroll
            for (int off = 32; off >= 1; off >>= 1) {
                int o = __shfl_xor(v, off);
                v = o < v ? o : v;
            }
            cand = v;
        }
        if ((tid & 63) == 0) {
            sKey[par][tid >> 6] =
                ((unsigned long long)__float_as_uint(wmax) << 32) |
                (unsigned long long)(0xFFFFFFFFu - (unsigned)cand);
        }
        __syncthreads();                   // the ONLY barrier per step
        unsigned long long k = sKey[par][0];
        #pragma unroll
        for (int i = 1; i < FWV; i++) {
            unsigned long long o = sKey[par][i];
            k = (o > k) ? o : k;
        }
        int p = (int)(0xFFFFFFFFu - (unsigned)(k & 0xFFFFFFFFull));
        float4 c4 = p4[p];                 // uniform addr -> one dwordx4, L2-hot
        cx = c4.x; cy = c4.y; cz = c4.z;
    }

    __syncthreads();                       // sHist complete
    float4* o4 = (float4*)(out_xyz + b * Sn * 3);
    const float4* h4 = (const float4*)sHist;
    for (int i = tid; i < Sn * 3 / 4; i += FTH) o4[i] = h4[i];
}

// ---------------------------------------------------------------------------
// Ball query, f32, mirroring the numpy transpile with einsum lowered to
// BLAS sgemm: the k=3 dot is an FMA chain acc=fma(a_k,b_k,acc) from 0.
// Norm terms are plain mul/add ((x2+y2)+z2). sq = (t1+t2) - 2*dot.
// One wave per (b,s). First K hits in ascending index order via
// ballot + prefix-popcount, early exit, pad with first hit.
// ---------------------------------------------------------------------------
__global__ __launch_bounds__(256) void ballq_kernel(const float* __restrict__ ws,
                                                    const float* __restrict__ newxyz,
                                                    int* __restrict__ grp) {
    #pragma clang fp contract(off)
    int t = blockIdx.x * 256 + threadIdx.x;
    int wid = t >> 6;            // 0..8191  (b*S+s)
    int lane = t & 63;
    int b = wid >> 11;
    const float4* p4 = (const float4*)(ws + WS_P4) + b * Nn;

    float nx = newxyz[wid * 3 + 0], ny = newxyz[wid * 3 + 1], nz = newxyz[wid * 3 + 2];
    float a2 = (nx * nx + ny * ny) + nz * nz;   // np.sum(new**2, -1): plain mul/add

    int total = 0;
    int firstp = 0;
    for (int c = 0; c < Nn / 64; c++) {
        int p = c * 64 + lane;
        float4 v = p4[p];
        float x = v.x, y = v.y, z = v.z;
        float bv = (x * x + y * y) + z * z;          // np.sum(xyz**2, -1)
        // sgemm k-loop: FMA rank-1 updates in order, acc starts at 0
        float dot = __builtin_fmaf(nx, x, 0.0f);
        dot = __builtin_fmaf(ny, y, dot);
        dot = __builtin_fmaf(nz, z, dot);
        float sq = (a2 + bv) - 2.0f * dot;           // (t1+t2) - 2*e
        bool hit = !(sq > R2c);
        unsigned long long mask = __ballot(hit);
        if (mask) {
            if (total == 0) firstp = c * 64 + (__ffsll(mask) - 1);
            int rank = __popcll(mask & ((1ull << lane) - 1ull));
            int slot = total + rank;
            if (hit && slot < Kn) grp[wid * Kn + slot] = p;
            total += (int)__popcll(mask);
            if (total >= Kn) break;
        }
    }
    if (lane >= total && lane < Kn) grp[wid * Kn + lane] = firstp;  // pad w/ first hit
}

// ---------------------------------------------------------------------------
// Fused gather + 3-layer MLP + maxpool (f32 — error ~1e-5 « 0.064 budget).
// ---------------------------------------------------------------------------
template<int C, int O, int WO>
__device__ __forceinline__ void mlp_layer(const float* inT, float* outT,
                                          const float* __restrict__ wt,
                                          const float* __restrict__ bias,
                                          int kt, int ot) {
    float acc[4][WO];
    #pragma unroll
    for (int oo = 0; oo < WO; oo++) {
        float bb = bias[ot * WO + oo];
        #pragma unroll
        for (int kk = 0; kk < 4; kk++) acc[kk][oo] = bb;
    }
    for (int c = 0; c < C; c++) {
        float4 hv = *(const float4*)&inT[c * KPAD + kt * 4];
        float ha[4] = {hv.x, hv.y, hv.z, hv.w};
        const float* wp = wt + c * O + ot * WO;
        float wv[WO];
        if constexpr (WO == 2) {
            float2 w = *(const float2*)wp; wv[0] = w.x; wv[1] = w.y;
        } else if constexpr (WO == 4) {
            float4 w = *(const float4*)wp; wv[0] = w.x; wv[1] = w.y; wv[2] = w.z; wv[3] = w.w;
        } else {
            float4 w0 = *(const float4*)wp, w1 = *(const float4*)(wp + 4);
            wv[0] = w0.x; wv[1] = w0.y; wv[2] = w0.z; wv[3] = w0.w;
            wv[4] = w1.x; wv[5] = w1.y; wv[6] = w1.z; wv[7] = w1.w;
        }
        #pragma unroll
        for (int kk = 0; kk < 4; kk++)
            #pragma unroll
            for (int oo = 0; oo < WO; oo++) acc[kk][oo] += ha[kk] * wv[oo];
    }
    #pragma unroll
    for (int oo = 0; oo < WO; oo++) {
        int o = ot * WO + oo;
        float4 st;
        st.x = fmaxf(acc[0][oo], 0.f); st.y = fmaxf(acc[1][oo], 0.f);
        st.z = fmaxf(acc[2][oo], 0.f); st.w = fmaxf(acc[3][oo], 0.f);
        *(float4*)&outT[o * KPAD + kt * 4] = st;
    }
}

__global__ __launch_bounds__(256, 3) void mlp_kernel(const float* __restrict__ xyz,
                                                     const float* __restrict__ feat,
                                                     const float* __restrict__ ws,
                                                     const int* __restrict__ grp,
                                                     const float* __restrict__ b1,
                                                     const float* __restrict__ b2,
                                                     const float* __restrict__ b3,
                                                     float* __restrict__ out) {
    __shared__ float h0[67 * KPAD];
    __shared__ float h1[64 * KPAD];
    __shared__ float h2[128 * KPAD];
    __shared__ float mxs[8 * 256];
    __shared__ int   sIdx[Kn];
    __shared__ float sCent[3];

    int g = blockIdx.x;            // b*S + s
    int b = g >> 11;
    int tid = threadIdx.x;

    if (tid < Kn) sIdx[tid] = grp[g * Kn + tid];
    if (tid == 0) { sCent[0] = out[g*3]; sCent[1] = out[g*3+1]; sCent[2] = out[g*3+2]; }
    __syncthreads();

    { // gather: 8 threads per neighbor row
        int k = tid >> 3, m = tid & 7;
        int idx = sIdx[k];
        int base = b * Nn + idx;
        if (m == 0) {
            h0[0 * KPAD + k] = xyz[base * 3 + 0] - sCent[0];
            h0[1 * KPAD + k] = xyz[base * 3 + 1] - sCent[1];
            h0[2 * KPAD + k] = xyz[base * 3 + 2] - sCent[2];
        }
        const float4* f4 = (const float4*)(feat + base * 64 + m * 8);
        float4 a = f4[0], c4 = f4[1];
        int r = 3 + m * 8;
        h0[(r + 0) * KPAD + k] = a.x;  h0[(r + 1) * KPAD + k] = a.y;
        h0[(r + 2) * KPAD + k] = a.z;  h0[(r + 3) * KPAD + k] = a.w;
        h0[(r + 4) * KPAD + k] = c4.x; h0[(r + 5) * KPAD + k] = c4.y;
        h0[(r + 6) * KPAD + k] = c4.z; h0[(r + 7) * KPAD + k] = c4.w;
    }
    __syncthreads();

    int ot = tid & 31, kt = tid >> 5;

    mlp_layer<67, 64, 2>(h0, h1, ws + WS_W1T, b1, kt, ot);
    __syncthreads();
    mlp_layer<64, 128, 4>(h1, h2, ws + WS_W2T, b2, kt, ot);
    __syncthreads();

    { // L3 (128 -> 256) fused with maxpool over the thread's 4 k-rows
        float acc[4][8];
        #pragma unroll
        for (int oo = 0; oo < 8; oo++) {
            float bb = b3[ot * 8 + oo];
            #pragma unroll
            for (int kk = 0; kk < 4; kk++) acc[kk][oo] = bb;
        }
        const float* wt = ws + WS_W3T;
        for (int c = 0; c < 128; c++) {
            float4 hv = *(const float4*)&h2[c * KPAD + kt * 4];
            float ha[4] = {hv.x, hv.y, hv.z, hv.w};
            const float* wp = wt + c * 256 + ot * 8;
            float4 w0 = *(const float4*)wp, w1 = *(const float4*)(wp + 4);
            float wv[8] = {w0.x, w0.y, w0.z, w0.w, w1.x, w1.y, w1.z, w1.w};
            #pragma unroll
            for (int kk = 0; kk < 4; kk++)
                #pragma unroll
                for (int oo = 0; oo < 8; oo++) acc[kk][oo] += ha[kk] * wv[oo];
        }
        #pragma unroll
        for (int oo = 0; oo < 8; oo++) {
            float m = fmaxf(fmaxf(acc[0][oo], acc[1][oo]), fmaxf(acc[2][oo], acc[3][oo]));
            mxs[kt * 256 + ot * 8 + oo] = fmaxf(m, 0.f);   // relu(max) == max(relu)
        }
    }
    __syncthreads();

    { // reduce the 8 k-tiles, write feats
        int o = tid;
        float m = mxs[o];
        #pragma unroll
        for (int q = 1; q < 8; q++) m = fmaxf(m, mxs[q * 256 + o]);
        out[OUT_XYZ + g * 256 + o] = m;
    }
}

// ---------------------------------------------------------------------------
extern "C" void kernel_launch(void* const* d_in, const int* in_sizes, int n_in,
                              void* d_out, int out_size, void* d_ws, size_t ws_size,
                              hipStream_t stream) {
    const float* xyz  = (const float*)d_in[0];
    const float* feat = (const float*)d_in[1];
    const float* W1   = (const float*)d_in[2];
    const float* b1   = (const float*)d_in[3];
    const float* W2   = (const float*)d_in[4];
    const float* b2   = (const float*)d_in[5];
    const float* W3   = (const float*)d_in[6];
    const float* b3   = (const float*)d_in[7];
    float* out = (float*)d_out;
    float* ws  = (float*)d_ws;
    int*   grp = (int*)d_ws + WS_GRP;

    hipLaunchKernelGGL(prep_kernel, dim3(305), dim3(256), 0, stream, xyz, W1, W2, W3, ws);
    hipLaunchKernelGGL(fps_kernel, dim3(Bn), dim3(FTH), 0, stream, ws, out);
    hipLaunchKernelGGL(ballq_kernel, dim3(Bn * Sn / 4), dim3(256), 0, stream, ws, out, grp);
    hipLaunchKernelGGL(mlp_kernel, dim3(Bn * Sn), dim3(256), 0, stream,
                       xyz, feat, ws, grp, b1, b2, b3, out);
}

// Round 14
// 2673.977 us; speedup vs baseline: 1.5144x; 1.5144x over previous
//
#include <hip/hip_runtime.h>

// Problem constants
#define Bn 4
#define Nn 8192
#define Dn 64
#define Sn 2048
#define Kn 32
#define R2c 0.04f          // f32(0.2*0.2)
#define OUT_XYZ (Bn*Sn*3)  // 24576 floats of new_xyz, then feats

// Workspace layout (units = 4-byte elements)
#define WS_P4  0            // [B*N] float4 {x,y,z,0}
#define WS_WB1 131072       // bf16 W1' [64][96]  (feat-first permute, zero pad)
#define WS_WB2 134144       // bf16 W2  [128][64]
#define WS_WB3 138240       // bf16 W3  [256][128]
#define WS_GRP 154624       // int grp_idx [B*S][K]

#define HSTR 136            // bf16 LDS row stride (128 max C + 8 pad)

typedef __attribute__((ext_vector_type(8))) short short8;
typedef __attribute__((ext_vector_type(4))) float floatx4;

// float -> bf16 (RNE) without relying on header APIs
__device__ __forceinline__ unsigned short f2bf(float f) {
    unsigned u = __float_as_uint(f);
    return (unsigned short)((u + 0x7FFFu + ((u >> 16) & 1u)) >> 16);
}

// ---------------------------------------------------------------------------
// Prep: xyz -> float4 array; weights -> bf16 [O][Cp] row-major.
// W1 channel-permuted: c'<64 = feat chans (orig 3..66), c' 64..66 = xyz
// (orig 0..2), 67..95 = 0. W2/W3 copied as-is (natural [O][C] layout).
// ---------------------------------------------------------------------------
__global__ __launch_bounds__(256) void prep_kernel(const float* __restrict__ xyz,
                                                   const float* __restrict__ W1,
                                                   const float* __restrict__ W2,
                                                   const float* __restrict__ W3,
                                                   float* __restrict__ ws) {
    int id = blockIdx.x * 256 + threadIdx.x;
    if (id < Bn * Nn) {
        float4* p4 = (float4*)(ws + WS_P4);
        p4[id] = make_float4(xyz[id * 3 + 0], xyz[id * 3 + 1], xyz[id * 3 + 2], 0.f);
    }
    int i1 = id - Bn * Nn;
    if (i1 >= 0 && i1 < 64 * 96) {
        int o = i1 / 96, c = i1 % 96;
        float v = (c < 64) ? W1[o * 67 + 3 + c] : (c < 67 ? W1[o * 67 + (c - 64)] : 0.f);
        ((unsigned short*)(ws + WS_WB1))[i1] = f2bf(v);
    }
    int i2 = i1 - 64 * 96;
    if (i2 >= 0 && i2 < 128 * 64)
        ((unsigned short*)(ws + WS_WB2))[i2] = f2bf(W2[i2]);
    int i3 = i2 - 128 * 64;
    if (i3 >= 0 && i3 < 256 * 128)
        ((unsigned short*)(ws + WS_WB3))[i3] = f2bf(W3[i3]);
}

// DPP wave-64 max (VALU pipe); lane 63 holds full-wave max, broadcast via readlane.
__device__ __forceinline__ float wave_fmax_dpp(float x) {
    float t;
    t = __int_as_float(__builtin_amdgcn_update_dpp(0, __float_as_int(x), 0x111, 0xf, 0xf, true)); x = fmaxf(x, t);
    t = __int_as_float(__builtin_amdgcn_update_dpp(0, __float_as_int(x), 0x112, 0xf, 0xf, true)); x = fmaxf(x, t);
    t = __int_as_float(__builtin_amdgcn_update_dpp(0, __float_as_int(x), 0x114, 0xf, 0xf, true)); x = fmaxf(x, t);
    t = __int_as_float(__builtin_amdgcn_update_dpp(0, __float_as_int(x), 0x118, 0xf, 0xf, true)); x = fmaxf(x, t);
    t = __int_as_float(__builtin_amdgcn_update_dpp(0, __float_as_int(x), 0x142, 0xf, 0xf, true)); x = fmaxf(x, t);
    t = __int_as_float(__builtin_amdgcn_update_dpp(0, __float_as_int(x), 0x143, 0xf, 0xf, true)); x = fmaxf(x, t);
    return __int_as_float(__builtin_amdgcn_readlane(__float_as_int(x), 63));
}

// ---------------------------------------------------------------------------
// Farthest point sampling — exact R10 config (best measured: 2417 us).
// 512 thr x 16 pts, value-only dist loop (bit-exact ref op order, contract
// off), DPP wave max, rare-path first-occurrence index recovery, ONE
// barrier/step, uniform L2 winner fetch, LDS hist + coalesced dump.
// R4-R13 established this is the structural plateau for a 4-CU sequential
// FPS; further barrier/register/occupancy tweaks are all neutral-to-worse.
// ---------------------------------------------------------------------------
__global__ __launch_bounds__(512, 2) void fps_kernel(const float* __restrict__ ws,
                                                     float* __restrict__ out_xyz) {
    #pragma clang fp contract(off)
    const int b = blockIdx.x;
    const int tid = threadIdx.x;
    const float4* p4 = (const float4*)(ws + WS_P4) + b * Nn;

    float px[16], py[16], pz[16], dist[16];
    #pragma unroll
    for (int j = 0; j < 16; j++) {
        float4 v = p4[j * 512 + tid];
        px[j] = v.x; py[j] = v.y; pz[j] = v.z;
        dist[j] = 1e10f;
    }
    #pragma unroll
    for (int j = 0; j < 16; j++) {
        asm volatile("" : "+v"(px[j]), "+v"(py[j]), "+v"(pz[j]), "+v"(dist[j]));
    }

    __shared__ unsigned long long sKey[2][8];
    __shared__ float sHist[Sn * 3];

    float4 c0 = p4[0];
    float cx = c0.x, cy = c0.y, cz = c0.z;

    for (int s = 0; s < Sn; s++) {
        const int par = s & 1;
        if (tid == 0) {
            sHist[s * 3 + 0] = cx;
            sHist[s * 3 + 1] = cy;
            sHist[s * 3 + 2] = cz;
        }
        float lv = -1.0f;
        #pragma unroll
        for (int j = 0; j < 16; j++) {
            float dx = px[j] - cx, dy = py[j] - cy, dz = pz[j] - cz;
            float d  = (dx * dx + dy * dy) + dz * dz;
            float dm = fminf(dist[j], d);
            dist[j] = dm;
            lv = fmaxf(lv, dm);
        }
        float wmax = wave_fmax_dpp(lv);
        int pb = 0x7fffffff;
        bool match = (lv == wmax);
        if (match) {
            #pragma unroll
            for (int j = 15; j >= 0; j--)
                if (dist[j] == wmax) pb = j * 512 + tid;
        }
        unsigned long long mask = __ballot(match);
        int cand;
        if (__popcll(mask) == 1) {
            cand = __builtin_amdgcn_readlane(pb, (int)(__ffsll(mask) - 1));
        } else {
            int v = pb;
            #pragma unroll
            for (int off = 32; off >= 1; off >>= 1) {
                int o = __shfl_xor(v, off);
                v = o < v ? o : v;
            }
            cand = v;
        }
        if ((tid & 63) == 0) {
            sKey[par][tid >> 6] =
                ((unsigned long long)__float_as_uint(wmax) << 32) |
                (unsigned long long)(0xFFFFFFFFu - (unsigned)cand);
        }
        __syncthreads();
        unsigned long long k = sKey[par][0];
        #pragma unroll
        for (int i = 1; i < 8; i++) {
            unsigned long long o = sKey[par][i];
            k = (o > k) ? o : k;
        }
        int p = (int)(0xFFFFFFFFu - (unsigned)(k & 0xFFFFFFFFull));
        float4 c4 = p4[p];
        cx = c4.x; cy = c4.y; cz = c4.z;
    }

    __syncthreads();
    float4* o4 = (float4*)(out_xyz + b * Sn * 3);
    const float4* h4 = (const float4*)sHist;
    #pragma unroll
    for (int i = tid; i < Sn * 3 / 4; i += 512) o4[i] = h4[i];
}

// ---------------------------------------------------------------------------
// Ball query (unchanged; exact-decision verified: absmax 0.0).
// ---------------------------------------------------------------------------
__global__ __launch_bounds__(256) void ballq_kernel(const float* __restrict__ ws,
                                                    const float* __restrict__ newxyz,
                                                    int* __restrict__ grp) {
    #pragma clang fp contract(off)
    int t = blockIdx.x * 256 + threadIdx.x;
    int wid = t >> 6;
    int lane = t & 63;
    int b = wid >> 11;
    const float4* p4 = (const float4*)(ws + WS_P4) + b * Nn;

    float nx = newxyz[wid * 3 + 0], ny = newxyz[wid * 3 + 1], nz = newxyz[wid * 3 + 2];
    float a2 = (nx * nx + ny * ny) + nz * nz;

    int total = 0;
    int firstp = 0;
    for (int c = 0; c < Nn / 64; c++) {
        int p = c * 64 + lane;
        float4 v = p4[p];
        float x = v.x, y = v.y, z = v.z;
        float bv = (x * x + y * y) + z * z;
        float dot = __builtin_fmaf(nx, x, 0.0f);
        dot = __builtin_fmaf(ny, y, dot);
        dot = __builtin_fmaf(nz, z, dot);
        float sq = (a2 + bv) - 2.0f * dot;
        bool hit = !(sq > R2c);
        unsigned long long mask = __ballot(hit);
        if (mask) {
            if (total == 0) firstp = c * 64 + (__ffsll(mask) - 1);
            int rank = __popcll(mask & ((1ull << lane) - 1ull));
            int slot = total + rank;
            if (hit && slot < Kn) grp[wid * Kn + slot] = p;
            total += (int)__popcll(mask);
            if (total >= Kn) break;
        }
    }
    if (lane >= total && lane < Kn) grp[wid * Kn + lane] = firstp;
}

// ---------------------------------------------------------------------------
// MFMA MLP: one group per block, 256 threads = 4 waves.
// M=32 rows (2 m-tiles), layers (Cp->O): 96->64, 64->128, 128->256.
// h tiles in LDS as bf16 [32][HSTR]; weights bf16 [O][Cp] from global (L2-hot).
// Wave wv owns m-tile (wv&1) and n-tiles nt = (wv>>1), +2, ... A-frags loaded
// once per layer per wave; fp32 accumulate; bias folded into acc init (all 4
// C regs share n = lane&15); relu in epilogue. Verified gfx950 layouts:
//   A[m=lane&15][k=(lane>>4)*8+j],  B[n=lane&15][k=...],
//   D[m=(lane>>4)*4+reg][n=lane&15].
// L3 epilogue fuses maxpool: per-lane max over 4 rows -> shfl_xor(16,32)
// across quads -> mxs[mt][n]; final = fmax over the two m-tiles.
// Error budget: bf16-rounded inputs, fp32 acc -> ~0.01-0.03 absmax;
// threshold 0.064 = 8 x bf16_eps x max|ref| is sized for exactly this.
// ---------------------------------------------------------------------------
template<int KB, int O>
__device__ __forceinline__ void mfma_layer(const unsigned short* __restrict__ X,
                                           unsigned short* __restrict__ Y,
                                           const unsigned short* __restrict__ wb,
                                           const float* __restrict__ bias,
                                           int lane, int wv) {
    const int Cp = KB * 32;
    const int mt = wv & 1;
    const int mrow = mt * 16 + (lane & 15);
    const int quad = lane >> 4;

    short8 a[KB];
    #pragma unroll
    for (int kb = 0; kb < KB; kb++)
        a[kb] = *(const short8*)&X[mrow * HSTR + kb * 32 + quad * 8];

    for (int nt = (wv >> 1); nt < O / 16; nt += 2) {
        int n0 = nt * 16;
        float bv = bias[n0 + (lane & 15)];
        floatx4 acc = {bv, bv, bv, bv};
        #pragma unroll
        for (int kb = 0; kb < KB; kb++) {
            short8 bf = *(const short8*)&wb[(n0 + (lane & 15)) * Cp + kb * 32 + quad * 8];
            acc = __builtin_amdgcn_mfma_f32_16x16x32_bf16(a[kb], bf, acc, 0, 0, 0);
        }
        #pragma unroll
        for (int r = 0; r < 4; r++) {
            float v = fmaxf(acc[r], 0.f);
            int m = mt * 16 + quad * 4 + r;
            Y[m * HSTR + n0 + (lane & 15)] = f2bf(v);
        }
    }
}

__global__ __launch_bounds__(256) void mlp_kernel(const float* __restrict__ xyz,
                                                  const float* __restrict__ feat,
                                                  const float* __restrict__ ws,
                                                  const int* __restrict__ grp,
                                                  const float* __restrict__ b1,
                                                  const float* __restrict__ b2,
                                                  const float* __restrict__ b3,
                                                  float* __restrict__ out) {
    __shared__ __align__(16) unsigned short hA[32 * HSTR];
    __shared__ __align__(16) unsigned short hB[32 * HSTR];
    __shared__ float mxs[2][256];
    __shared__ int   sIdx[Kn];
    __shared__ float sCent[3];

    int g = blockIdx.x;            // b*S + s
    int b = g >> 11;
    int tid = threadIdx.x;
    int lane = tid & 63, wv = tid >> 6;

    if (tid < Kn) sIdx[tid] = grp[g * Kn + tid];
    if (tid == 0) { sCent[0] = out[g*3]; sCent[1] = out[g*3+1]; sCent[2] = out[g*3+2]; }
    // zero hA (pad cols must be 0 for the K=96 layer)
    {
        short8 z = {0,0,0,0,0,0,0,0};
        for (int i = tid; i < 32 * HSTR / 8; i += 256)
            ((short8*)hA)[i] = z;
    }
    __syncthreads();

    { // stage h0: feats -> cols 0..63 (bf16x8 vector writes), xyz -> 64..66
        int m = tid >> 3, m8 = tid & 7;
        int idx = sIdx[m];
        int base = b * Nn + idx;
        const float4* f4 = (const float4*)(feat + base * 64 + m8 * 8);
        float4 va = f4[0], vb = f4[1];
        short8 pk;
        pk[0] = (short)f2bf(va.x); pk[1] = (short)f2bf(va.y);
        pk[2] = (short)f2bf(va.z); pk[3] = (short)f2bf(va.w);
        pk[4] = (short)f2bf(vb.x); pk[5] = (short)f2bf(vb.y);
        pk[6] = (short)f2bf(vb.z); pk[7] = (short)f2bf(vb.w);
        *(short8*)&hA[m * HSTR + m8 * 8] = pk;
        if (m8 == 0) {
            hA[m * HSTR + 64] = f2bf(xyz[base * 3 + 0] - sCent[0]);
            hA[m * HSTR + 65] = f2bf(xyz[base * 3 + 1] - sCent[1]);
            hA[m * HSTR + 66] = f2bf(xyz[base * 3 + 2] - sCent[2]);
        }
    }
    __syncthreads();

    const unsigned short* wb1 = (const unsigned short*)(ws + WS_WB1);
    const unsigned short* wb2 = (const unsigned short*)(ws + WS_WB2);
    const unsigned short* wb3 = (const unsigned short*)(ws + WS_WB3);

    mfma_layer<3, 64>(hA, hB, wb1, b1, lane, wv);     // 96 -> 64
    __syncthreads();
    mfma_layer<2, 128>(hB, hA, wb2, b2, lane, wv);    // 64 -> 128
    __syncthreads();

    { // L3 (128 -> 256) + fused maxpool
        const int mt = wv & 1;
        const int mrow = mt * 16 + (lane & 15);
        const int quad = lane >> 4;
        short8 a[4];
        #pragma unroll
        for (int kb = 0; kb < 4; kb++)
            a[kb] = *(const short8*)&hA[mrow * HSTR + kb * 32 + quad * 8];
        for (int nt = (wv >> 1); nt < 16; nt += 2) {
            int n0 = nt * 16;
            float bv = b3[n0 + (lane & 15)];
            floatx4 acc = {bv, bv, bv, bv};
            #pragma unroll
            for (int kb = 0; kb < 4; kb++) {
                short8 bf = *(const short8*)&wb3[(n0 + (lane & 15)) * 128 + kb * 32 + quad * 8];
                acc = __builtin_amdgcn_mfma_f32_16x16x32_bf16(a[kb], bf, acc, 0, 0, 0);
            }
            float pm = fmaxf(fmaxf(fmaxf(acc[0], acc[1]), fmaxf(acc[2], acc[3])), 0.f);
            pm = fmaxf(pm, __shfl_xor(pm, 16));   // reduce across the 4 quads
            pm = fmaxf(pm, __shfl_xor(pm, 32));
            if (lane < 16) mxs[mt][n0 + lane] = pm;
        }
    }
    __syncthreads();

    out[OUT_XYZ + g * 256 + tid] = fmaxf(mxs[0][tid], mxs[1][tid]);
}

// ---------------------------------------------------------------------------
extern "C" void kernel_launch(void* const* d_in, const int* in_sizes, int n_in,
                              void* d_out, int out_size, void* d_ws, size_t ws_size,
                              hipStream_t stream) {
    const float* xyz  = (const float*)d_in[0];
    const float* feat = (const float*)d_in[1];
    const float* W1   = (const float*)d_in[2];
    const float* b1   = (const float*)d_in[3];
    const float* W2   = (const float*)d_in[4];
    const float* b2   = (const float*)d_in[5];
    const float* W3   = (const float*)d_in[6];
    const float* b3   = (const float*)d_in[7];
    float* out = (float*)d_out;
    float* ws  = (float*)d_ws;
    int*   grp = (int*)d_ws + WS_GRP;

    hipLaunchKernelGGL(prep_kernel, dim3(312), dim3(256), 0, stream, xyz, W1, W2, W3, ws);
    hipLaunchKernelGGL(fps_kernel, dim3(Bn), dim3(512), 0, stream, ws, out);
    hipLaunchKernelGGL(ballq_kernel, dim3(Bn * Sn / 4), dim3(256), 0, stream, ws, out, grp);
    hipLaunchKernelGGL(mlp_kernel, dim3(Bn * Sn), dim3(256), 0, stream,
                       xyz, feat, ws, grp, b1, b2, b3, out);
}